// Round 18
// baseline (1528.913 us; speedup 1.0000x reference)
//
#include <hip/hip_runtime.h>
#include <cstddef>

#define NN 256      // N
#define PP 256      // P
#define BB 128      // B
#define KK 4        // K
#define NSYS 512    // K*B
#define PW 32       // panel width
#define NPAN (NN/PW)

__device__ __forceinline__ float sigmoidf_(float x){ return 1.0f/(1.0f+expf(-x)); }

// ---------------------------------------------------------------------------
// Kernel 1: build Cm (A) and rowsum(Cm) for systems [s0,s0+cs)
// ---------------------------------------------------------------------------
__global__ __launch_bounds__(256) void build_kernel(
    const float* __restrict__ C, const float* __restrict__ rm,
    const float* __restrict__ epsp, const int* __restrict__ bad,
    float* __restrict__ A, float* __restrict__ rowsum, int s0)
{
  const int si = blockIdx.x;
  const int ls = si >> 8;
  const int i  = si & 255;
  const int s  = s0 + ls;
  const int k  = s >> 7;
  const int b  = s & 127;
  const int j  = threadIdx.x;

  const float sk = sigmoidf_(rm[k]);
  const float ek = sigmoidf_(epsp[k]);
  const bool bad_i = bad[b*NN + i] != 0;
  const bool bad_j = bad[b*NN + j] != 0;

  float c  = C[((size_t)b*NN + i)*(NN+PP) + j];
  float x  = sk * c;
  float cf = (1.0f + x) * expf(-x);
  if (i == j) cf += ek;              // diag: C[i][i]==0 -> cf==1, add eps
  float keep = (bad_i == bad_j) ? 1.0f : 0.0f;
  float a = cf * keep;
  A[((size_t)ls*NN + i)*NN + j] = a;

  __shared__ float red[256];
  red[j] = a; __syncthreads();
  #pragma unroll
  for (int off = 128; off > 0; off >>= 1){
    if (j < off) red[j] += red[j + off];
    __syncthreads();
  }
  if (j == 0) rowsum[ls*NN + i] = red[0];
}

// ---------------------------------------------------------------------------
// Kernel 2: swap-free blocked LU with partial pivoting ("pick-order").
// Rows never move: thread t owns physical row t; pivot order -> pivseq.
// (round-8/14 version — measured good: 64 VGPR, 2 blocks/CU, ~775 us)
// ---------------------------------------------------------------------------
__global__ __launch_bounds__(512, 4) void lu_kernel(
    float* __restrict__ Aall, int* __restrict__ permAll)
{
  __shared__ float panel[NN][PW+1];
  __shared__ float linv[PW][PW+1];
  __shared__ float uinv[PW][PW+1];
  __shared__ float urow[PW][NN-PW];
  __shared__ float redv[2][8];
  __shared__ int   redi[2][8];
  __shared__ int   pivseq[NN];
  __shared__ int   actlist[NN];
  __shared__ unsigned char pickedsh[NN];
  __shared__ int   nact;

  const int ls = blockIdx.x;
  float* __restrict__ A = Aall + (size_t)ls*NN*NN;
  const int t = threadIdx.x;
  const int lane = t & 63, wid = t >> 6;
  bool picked = false;
  if (t < NN) pickedsh[t] = 0;

  for (int I = 0; I < NPAN; ++I){
    const int col0 = I*PW;
    const int W = NN - col0 - PW;
    if (t == 0) nact = 0;
    __syncthreads();

    for (int e = t; e < NN*PW; e += 512){
      int r = e >> 5, c = e & 31;
      panel[r][c] = A[(size_t)r*NN + col0 + c];
    }
    __syncthreads();

    {
      float v = -1.0f; int vi = 0;
      if (t < NN && !picked){ v = fabsf(panel[t][0]); vi = t; }
      #pragma unroll
      for (int off = 32; off > 0; off >>= 1){
        float ov = __shfl_down(v, off); int oi = __shfl_down(vi, off);
        if (ov > v){ v = ov; vi = oi; }
      }
      if (lane == 0){ redv[0][wid] = v; redi[0][wid] = vi; }
    }
    __syncthreads();

    for (int c = 0; c < PW; ++c){
      const int par = c & 1;
      float bv = redv[par][0]; int p = redi[par][0];
      #pragma unroll
      for (int w = 1; w < 8; ++w)
        if (redv[par][w] > bv){ bv = redv[par][w]; p = redi[par][w]; }
      if (t == p){ picked = true; pickedsh[t] = 1; pivseq[col0+c] = t; }

      float nv = -1.0f; int ni = t;
      if (t < NN && !picked){
        const float rdia = 1.0f / panel[p][c];
        float m = panel[t][c] * rdia;
        panel[t][c] = m;
        float nxt = -1.0f;
        #pragma unroll
        for (int j = 0; j < PW; ++j){
          if (j > c){
            float u = panel[t][j] - m * panel[p][j];
            panel[t][j] = u;
            if (j == c+1) nxt = fabsf(u);
          }
        }
        nv = nxt;
      }
      #pragma unroll
      for (int off = 32; off > 0; off >>= 1){
        float ov = __shfl_down(nv, off); int oi = __shfl_down(ni, off);
        if (ov > nv){ nv = ov; ni = oi; }
      }
      if (lane == 0){ redv[par^1][wid] = nv; redi[par^1][wid] = ni; }
      __syncthreads();
    }

    if (t >= 256){
      const int jj = t - 256;
      if (jj < W){
        const int j = col0 + PW + jj;
        float u[PW];
        #pragma unroll
        for (int c = 0; c < PW; ++c) u[c] = A[(size_t)pivseq[col0+c]*NN + j];
        #pragma unroll
        for (int c = 0; c < PW; ++c){
          const int pc = pivseq[col0+c];
          float sv = u[c];
          #pragma unroll
          for (int k2 = 0; k2 < PW; ++k2)
            if (k2 < c) sv -= panel[pc][k2] * u[k2];
          u[c] = sv;
          urow[c][jj] = sv;
          A[(size_t)pc*NN + j] = sv;
        }
      }
    } else if (t < PW){
      const int cth = t;
      for (int r = cth; r < PW; ++r){
        float sv = (r == cth) ? 1.0f : 0.0f;
        const int pr = pivseq[col0+r];
        for (int k2 = cth; k2 < r; ++k2) sv -= panel[pr][k2] * linv[k2][cth];
        linv[r][cth] = sv;
      }
    } else if (t >= 64 && t < 64+PW){
      const int cth = t - 64;
      for (int r = cth; r >= 0; --r){
        float sv = (r == cth) ? 1.0f : 0.0f;
        const int pr = pivseq[col0+r];
        for (int k2 = r+1; k2 <= cth; ++k2) sv -= panel[pr][k2] * uinv[k2][cth];
        uinv[r][cth] = sv / panel[pr][r];
      }
    } else if (t >= 128 && t < 192){
      #pragma unroll
      for (int q = 0; q < 4; ++q){
        int r = (t-128)*4 + q;
        if (!pickedsh[r]){ int pos = atomicAdd(&nact, 1); actlist[pos] = r; }
      }
    }
    __syncthreads();

    for (int e = t; e < PW*PW; e += 512){
      int r = e >> 5, c2 = e & 31;
      A[(size_t)pivseq[col0+r]*NN + col0 + c2] = (r > c2) ? linv[r][c2] : uinv[r][c2];
    }
    for (int e = t; e < NN*PW; e += 512){
      int r = e >> 5, c2 = e & 31;
      if (!pickedsh[r]) A[(size_t)r*NN + col0 + c2] = panel[r][c2];
    }

    // ---- trailing update: active rows -= L21 * U12 (float4, 1 pass over cols) ----
    if (W > 0){
      for (int i0 = wid*2; i0 < W; i0 += 16){
        const int r0 = actlist[i0];
        const int r1 = actlist[i0+1];          // W is even: pair always valid
        float4* R0 = (float4*)(A + (size_t)r0*NN + col0 + PW);
        float4* R1 = (float4*)(A + (size_t)r1*NN + col0 + PW);
        if (lane*4 < W){
          float4 a0 = R0[lane];
          float4 a1 = R1[lane];
          #pragma unroll
          for (int c = 0; c < PW; ++c){
            float4 u4 = *(const float4*)&urow[c][lane*4];
            float p0 = panel[r0][c], p1 = panel[r1][c];
            a0.x -= p0*u4.x; a0.y -= p0*u4.y; a0.z -= p0*u4.z; a0.w -= p0*u4.w;
            a1.x -= p1*u4.x; a1.y -= p1*u4.y; a1.z -= p1*u4.z; a1.w -= p1*u4.w;
          }
          R0[lane] = a0;
          R1[lane] = a1;
        }
      }
    }
  }
  __syncthreads();
  if (t < NN) permAll[ls*NN + t] = pivseq[t];
}

// ---------------------------------------------------------------------------
// Kernel 3: blocked triangular solves + epilogue for ONE 128-col RHS chunk.
// 2 columns per thread (lane, lane+64). LDS 149KB -> 1 block/CU regardless,
// so declare __launch_bounds__(512, 2): allocator may use up to 256 VGPR
// (round-17 counters showed 128-VGPR cap spilled xa/xb: WRITE_SIZE 370 MB).
// ---------------------------------------------------------------------------
__global__ __launch_bounds__(512, 2) void solve_epi_kernel(
    const float* __restrict__ Aall, const int* __restrict__ permAll,
    const float* __restrict__ rowsum,
    const float* __restrict__ C, const float* __restrict__ val,
    const int* __restrict__ bad, const float* __restrict__ rm,
    float* __restrict__ out, int s0)
{
  __shared__ float tile[NN][128];             // 128 KiB
  __shared__ float dblk[PW][PW+1];            // 4.2 KiB
  __shared__ __align__(16) float ubuf[4096];  // 16 KiB: stage / epilogue partials
  __shared__ int   perm[NN];

  int ls, c0;
  {
    const int g = blockIdx.x;
    if ((gridDim.x & 15) == 0){       // cs % 8 == 0: XCD co-location swizzle
      const int xcd = g & 7, idx = g >> 3;
      ls = xcd + 8*(idx >> 1);
      c0 = (idx & 1) * 128;
    } else {
      ls = g >> 1;
      c0 = (g & 1) * 128;
    }
  }
  const int s  = s0 + ls;
  const int k  = s >> 7, b = s & 127;
  const float* __restrict__ A = Aall + (size_t)ls*NN*NN;
  const float* __restrict__ rs = rowsum + ls*NN;
  const int t = threadIdx.x;
  const int lane = t & 63, wid = t >> 6;
  const int lane2 = lane + 64;
  const float sk = sigmoidf_(rm[k]);
  const int slr = t >> 3;            // stage row owned by this thread
  const int sq4 = (t & 7) << 2;      // stage col offset (floats)

  if (t < NN) perm[t] = permAll[ls*NN + t];
  __syncthreads();

  // ---- build permuted RHS chunk on the fly (128 cols) ----
  for (int e = t; e < NN*128; e += 512){
    int i = e >> 7, c = e & 127;
    int pi = perm[i];
    float cb = C[((size_t)b*NN + pi)*(NN+PP) + NN + c0 + c];
    float xb = sk * cb;
    float bf = (1.0f + xb) * expf(-xb);
    if (bad[b*NN + pi]) bf = 0.0f;
    tile[i][c] = bf;
  }
  __syncthreads();

  // ---- forward: y = Linv-chain applied to Pb ----
  for (int J = 0; J < NPAN; ++J){
    const int j0 = J*PW;
    for (int e = t; e < PW*PW; e += 512){
      int r = e >> 5, c = e & 31;
      dblk[r][c] = A[(size_t)perm[j0+r]*NN + j0 + c];
    }
    __syncthreads();
    const int r0 = wid*4;
    float ya0 = tile[j0+r0+0][lane],  yb0 = tile[j0+r0+0][lane2];
    float ya1 = tile[j0+r0+1][lane],  yb1 = tile[j0+r0+1][lane2];
    float ya2 = tile[j0+r0+2][lane],  yb2 = tile[j0+r0+2][lane2];
    float ya3 = tile[j0+r0+3][lane],  yb3 = tile[j0+r0+3][lane2];
    for (int kk = 0; kk < r0; ++kk){
      float xa = tile[j0+kk][lane], xb = tile[j0+kk][lane2];
      float d0 = dblk[r0+0][kk], d1 = dblk[r0+1][kk], d2 = dblk[r0+2][kk], d3 = dblk[r0+3][kk];
      ya0 += d0*xa; yb0 += d0*xb;
      ya1 += d1*xa; yb1 += d1*xb;
      ya2 += d2*xa; yb2 += d2*xb;
      ya3 += d3*xa; yb3 += d3*xb;
    }
    {
      float xa0 = tile[j0+r0][lane],  xa1 = tile[j0+r0+1][lane],  xa2 = tile[j0+r0+2][lane];
      float xb0 = tile[j0+r0][lane2], xb1 = tile[j0+r0+1][lane2], xb2 = tile[j0+r0+2][lane2];
      float e10 = dblk[r0+1][r0];
      float e20 = dblk[r0+2][r0], e21 = dblk[r0+2][r0+1];
      float e30 = dblk[r0+3][r0], e31 = dblk[r0+3][r0+1], e32 = dblk[r0+3][r0+2];
      ya1 += e10*xa0;                         yb1 += e10*xb0;
      ya2 += e20*xa0 + e21*xa1;               yb2 += e20*xb0 + e21*xb1;
      ya3 += e30*xa0 + e31*xa1 + e32*xa2;     yb3 += e30*xb0 + e31*xb1 + e32*xb2;
    }
    __syncthreads();
    tile[j0+r0+0][lane]=ya0; tile[j0+r0+0][lane2]=yb0;
    tile[j0+r0+1][lane]=ya1; tile[j0+r0+1][lane2]=yb1;
    tile[j0+r0+2][lane]=ya2; tile[j0+r0+2][lane2]=yb2;
    tile[j0+r0+3][lane]=ya3; tile[j0+r0+3][lane2]=yb3;
    __syncthreads();
    const int nbelow = NN - j0 - PW;
    if (nbelow > 0){
      float xa[PW], xb[PW];
      #pragma unroll
      for (int kk = 0; kk < PW; ++kk){ xa[kk] = tile[j0+kk][lane]; xb[kk] = tile[j0+kk][lane2]; }
      for (int cb2 = 0; cb2 < nbelow; cb2 += 64){
        const int rows_c = (nbelow - cb2 < 64) ? (nbelow - cb2) : 64;   // 64 or 32
        if (t < rows_c*8)
          *(float4*)&ubuf[(slr<<5) + sq4] =
            *(const float4*)(A + (size_t)perm[j0+PW+cb2+slr]*NN + j0 + sq4);
        __syncthreads();
        const int rpw = rows_c >> 3;            // rows per wave: 8 or 4
        for (int p2 = 0; p2 < rpw; p2 += 2){
          const int lr0 = wid*rpw + p2;
          const int ia = j0 + PW + cb2 + lr0, ib = ia + 1;
          const float* __restrict__ S0 = &ubuf[lr0<<5];
          const float* __restrict__ S1 = &ubuf[(lr0+1)<<5];
          float a0a = tile[ia][lane], a0b = tile[ia][lane2];
          float a1a = tile[ib][lane], a1b = tile[ib][lane2];
          #pragma unroll
          for (int q = 0; q < 8; ++q){
            float4 a4 = *(const float4*)(S0 + (q<<2));
            float4 b4 = *(const float4*)(S1 + (q<<2));
            a0a -= a4.x*xa[q*4+0] + a4.y*xa[q*4+1] + a4.z*xa[q*4+2] + a4.w*xa[q*4+3];
            a0b -= a4.x*xb[q*4+0] + a4.y*xb[q*4+1] + a4.z*xb[q*4+2] + a4.w*xb[q*4+3];
            a1a -= b4.x*xa[q*4+0] + b4.y*xa[q*4+1] + b4.z*xa[q*4+2] + b4.w*xa[q*4+3];
            a1b -= b4.x*xb[q*4+0] + b4.y*xb[q*4+1] + b4.z*xb[q*4+2] + b4.w*xb[q*4+3];
          }
          tile[ia][lane] = a0a; tile[ia][lane2] = a0b;
          tile[ib][lane] = a1a; tile[ib][lane2] = a1b;
        }
        __syncthreads();
      }
    }
  }

  // ---- backward: d = Uinv-chain applied to y ----
  for (int J = NPAN-1; J >= 0; --J){
    const int j0 = J*PW;
    for (int e = t; e < PW*PW; e += 512){
      int r = e >> 5, c = e & 31;
      dblk[r][c] = A[(size_t)perm[j0+r]*NN + j0 + c];
    }
    __syncthreads();
    const int r0 = wid*4;
    float ya0=0.f, ya1=0.f, ya2=0.f, ya3=0.f;
    float yb0=0.f, yb1=0.f, yb2=0.f, yb3=0.f;
    for (int kk = r0+4; kk < PW; ++kk){
      float xa = tile[j0+kk][lane], xb = tile[j0+kk][lane2];
      float d0 = dblk[r0+0][kk], d1 = dblk[r0+1][kk], d2 = dblk[r0+2][kk], d3 = dblk[r0+3][kk];
      ya0 += d0*xa; yb0 += d0*xb;
      ya1 += d1*xa; yb1 += d1*xb;
      ya2 += d2*xa; yb2 += d2*xb;
      ya3 += d3*xa; yb3 += d3*xb;
    }
    {
      float xa0 = tile[j0+r0][lane],  xa1 = tile[j0+r0+1][lane];
      float xa2 = tile[j0+r0+2][lane], xa3 = tile[j0+r0+3][lane];
      float xb0 = tile[j0+r0][lane2],  xb1 = tile[j0+r0+1][lane2];
      float xb2 = tile[j0+r0+2][lane2], xb3 = tile[j0+r0+3][lane2];
      float e00=dblk[r0][r0], e01=dblk[r0][r0+1], e02=dblk[r0][r0+2], e03=dblk[r0][r0+3];
      float e11=dblk[r0+1][r0+1], e12=dblk[r0+1][r0+2], e13=dblk[r0+1][r0+3];
      float e22=dblk[r0+2][r0+2], e23=dblk[r0+2][r0+3];
      float e33=dblk[r0+3][r0+3];
      ya0 += e00*xa0 + e01*xa1 + e02*xa2 + e03*xa3;  yb0 += e00*xb0 + e01*xb1 + e02*xb2 + e03*xb3;
      ya1 += e11*xa1 + e12*xa2 + e13*xa3;            yb1 += e11*xb1 + e12*xb2 + e13*xb3;
      ya2 += e22*xa2 + e23*xa3;                      yb2 += e22*xb2 + e23*xb3;
      ya3 += e33*xa3;                                yb3 += e33*xb3;
    }
    __syncthreads();
    tile[j0+r0+0][lane]=ya0; tile[j0+r0+0][lane2]=yb0;
    tile[j0+r0+1][lane]=ya1; tile[j0+r0+1][lane2]=yb1;
    tile[j0+r0+2][lane]=ya2; tile[j0+r0+2][lane2]=yb2;
    tile[j0+r0+3][lane]=ya3; tile[j0+r0+3][lane2]=yb3;
    __syncthreads();
    if (j0 > 0){
      float xa[PW], xb[PW];
      #pragma unroll
      for (int kk = 0; kk < PW; ++kk){ xa[kk] = tile[j0+kk][lane]; xb[kk] = tile[j0+kk][lane2]; }
      for (int cb2 = 0; cb2 < j0; cb2 += 64){
        const int rows_c = (j0 - cb2 < 64) ? (j0 - cb2) : 64;   // 64 or 32
        if (t < rows_c*8)
          *(float4*)&ubuf[(slr<<5) + sq4] =
            *(const float4*)(A + (size_t)perm[cb2+slr]*NN + j0 + sq4);
        __syncthreads();
        const int rpw = rows_c >> 3;
        for (int p2 = 0; p2 < rpw; p2 += 2){
          const int lr0 = wid*rpw + p2;
          const int ia = cb2 + lr0, ib = ia + 1;
          const float* __restrict__ S0 = &ubuf[lr0<<5];
          const float* __restrict__ S1 = &ubuf[(lr0+1)<<5];
          float a0a = tile[ia][lane], a0b = tile[ia][lane2];
          float a1a = tile[ib][lane], a1b = tile[ib][lane2];
          #pragma unroll
          for (int q = 0; q < 8; ++q){
            float4 a4 = *(const float4*)(S0 + (q<<2));
            float4 b4 = *(const float4*)(S1 + (q<<2));
            a0a -= a4.x*xa[q*4+0] + a4.y*xa[q*4+1] + a4.z*xa[q*4+2] + a4.w*xa[q*4+3];
            a0b -= a4.x*xb[q*4+0] + a4.y*xb[q*4+1] + a4.z*xb[q*4+2] + a4.w*xb[q*4+3];
            a1a -= b4.x*xa[q*4+0] + b4.y*xa[q*4+1] + b4.z*xa[q*4+2] + b4.w*xa[q*4+3];
            a1b -= b4.x*xb[q*4+0] + b4.y*xb[q*4+1] + b4.z*xb[q*4+2] + b4.w*xb[q*4+3];
          }
          tile[ia][lane] = a0a; tile[ia][lane2] = a0b;
          tile[ib][lane] = a1a; tile[ib][lane2] = a1b;
        }
        __syncthreads();
      }
    }
  }

  // ---- epilogue: 8-wave partial column reductions (2 cols/thread) ----
  {
    float sdva=0.f, sabsa=0.f, s1va=0.f, s1a=0.f;
    float sdvb=0.f, sabsb=0.f, s1vb=0.f, s1b=0.f;
    const int pa = c0 + lane, pb = c0 + lane2;
    for (int j = wid*32; j < wid*32 + 32; ++j){
      float v = val[(b*NN + j)*KK + k];
      if (v != v) v = 0.0f;
      const float rsj = rs[j];
      const bool bj = bad[b*NN + j] != 0;
      float da = tile[j][lane];
      float cba = C[((size_t)b*NN + j)*(NN+PP) + NN + pa];
      float xba = sk*cba;
      float boa = (1.0f+xba)*expf(-xba);
      if (bj) boa = 0.0f;
      float d1a = boa / rsj;
      sdva += da*v; sabsa += fabsf(da); s1va += d1a*v; s1a += d1a;
      float db = tile[j][lane2];
      float cbb = C[((size_t)b*NN + j)*(NN+PP) + NN + pb];
      float xbb = sk*cbb;
      float bob = (1.0f+xbb)*expf(-xbb);
      if (bj) bob = 0.0f;
      float d1b = bob / rsj;
      sdvb += db*v; sabsb += fabsf(db); s1vb += d1b*v; s1b += d1b;
    }
    __syncthreads();   // ubuf (stage) dead; reuse as ep partials
    ubuf[(0*8 + wid)*128 + lane] = sdva;  ubuf[(0*8 + wid)*128 + lane2] = sdvb;
    ubuf[(1*8 + wid)*128 + lane] = sabsa; ubuf[(1*8 + wid)*128 + lane2] = sabsb;
    ubuf[(2*8 + wid)*128 + lane] = s1va;  ubuf[(2*8 + wid)*128 + lane2] = s1vb;
    ubuf[(3*8 + wid)*128 + lane] = s1a;   ubuf[(3*8 + wid)*128 + lane2] = s1b;
  }
  __syncthreads();
  if (t < 128){
    float sdv=0.f, sabs=0.f, s1v=0.f, s1=0.f;
    #pragma unroll
    for (int w = 0; w < 8; ++w){
      sdv  += ubuf[(0*8 + w)*128 + t];
      sabs += ubuf[(1*8 + w)*128 + t];
      s1v  += ubuf[(2*8 + w)*128 + t];
      s1   += ubuf[(3*8 + w)*128 + t];
    }
    float wg    = fminf(fmaxf((sabs - 1.0f)*2.0f, 0.0f), 1.0f);
    float denom = fmaxf(s1, 1.0f);
    out[((size_t)b*PP + c0 + t)*KK + k] = (1.0f - wg)*sdv + (wg/denom)*s1v;
  }
}

// ---------------------------------------------------------------------------
extern "C" void kernel_launch(void* const* d_in, const int* in_sizes, int n_in,
                              void* d_out, int out_size, void* d_ws, size_t ws_size,
                              hipStream_t stream)
{
  (void)in_sizes; (void)n_in; (void)out_size;
  const float* C    = (const float*)d_in[0];
  const float* val  = (const float*)d_in[1];
  const float* rm   = (const float*)d_in[2];
  const float* epsp = (const float*)d_in[3];
  const int*   bad  = (const int*)d_in[4];
  float* out = (float*)d_out;

  // per-system workspace: A (NN*NN f32) + rowsum (NN f32) + perm (NN i32)
  const size_t per_sys = (size_t)NN*NN*4 + (size_t)NN*4 + (size_t)NN*4;
  int chunk = (int)(ws_size / per_sys);
  if (chunk < 1)    chunk = 1;
  if (chunk > NSYS) chunk = NSYS;

  float* ws     = (float*)d_ws;
  float* A      = ws;
  float* rowsum = A + (size_t)chunk*NN*NN;
  int*   perm   = (int*)(rowsum + (size_t)chunk*NN);

  for (int s0 = 0; s0 < NSYS; s0 += chunk){
    int cs = (NSYS - s0 < chunk) ? (NSYS - s0) : chunk;
    build_kernel<<<cs*NN, 256, 0, stream>>>(C, rm, epsp, bad, A, rowsum, s0);
    lu_kernel<<<cs, 512, 0, stream>>>(A, perm);
    solve_epi_kernel<<<cs*2, 512, 0, stream>>>(A, perm, rowsum, C, val, bad, rm, out, s0);
  }
}

// Round 19
// 1413.656 us; speedup vs baseline: 1.0815x; 1.0815x over previous
//
#include <hip/hip_runtime.h>
#include <cstddef>

#define NN 256      // N
#define PP 256      // P
#define BB 128      // B
#define KK 4        // K
#define NSYS 512    // K*B
#define PW 32       // panel width
#define NPAN (NN/PW)

__device__ __forceinline__ float sigmoidf_(float x){ return 1.0f/(1.0f+expf(-x)); }

// ---------------------------------------------------------------------------
// Kernel 1: build Cm (A) and rowsum(Cm) for systems [s0,s0+cs)
// ---------------------------------------------------------------------------
__global__ __launch_bounds__(256) void build_kernel(
    const float* __restrict__ C, const float* __restrict__ rm,
    const float* __restrict__ epsp, const int* __restrict__ bad,
    float* __restrict__ A, float* __restrict__ rowsum, int s0)
{
  const int si = blockIdx.x;
  const int ls = si >> 8;
  const int i  = si & 255;
  const int s  = s0 + ls;
  const int k  = s >> 7;
  const int b  = s & 127;
  const int j  = threadIdx.x;

  const float sk = sigmoidf_(rm[k]);
  const float ek = sigmoidf_(epsp[k]);
  const bool bad_i = bad[b*NN + i] != 0;
  const bool bad_j = bad[b*NN + j] != 0;

  float c  = C[((size_t)b*NN + i)*(NN+PP) + j];
  float x  = sk * c;
  float cf = (1.0f + x) * expf(-x);
  if (i == j) cf += ek;              // diag: C[i][i]==0 -> cf==1, add eps
  float keep = (bad_i == bad_j) ? 1.0f : 0.0f;
  float a = cf * keep;
  A[((size_t)ls*NN + i)*NN + j] = a;

  __shared__ float red[256];
  red[j] = a; __syncthreads();
  #pragma unroll
  for (int off = 128; off > 0; off >>= 1){
    if (j < off) red[j] += red[j + off];
    __syncthreads();
  }
  if (j == 0) rowsum[ls*NN + i] = red[0];
}

// ---------------------------------------------------------------------------
// Kernel 2: swap-free blocked LU with partial pivoting ("pick-order").
// (round-8/14 version — measured good: 64 VGPR, 2 blocks/CU, ~775 us)
// ---------------------------------------------------------------------------
__global__ __launch_bounds__(512, 4) void lu_kernel(
    float* __restrict__ Aall, int* __restrict__ permAll)
{
  __shared__ float panel[NN][PW+1];
  __shared__ float linv[PW][PW+1];
  __shared__ float uinv[PW][PW+1];
  __shared__ float urow[PW][NN-PW];
  __shared__ float redv[2][8];
  __shared__ int   redi[2][8];
  __shared__ int   pivseq[NN];
  __shared__ int   actlist[NN];
  __shared__ unsigned char pickedsh[NN];
  __shared__ int   nact;

  const int ls = blockIdx.x;
  float* __restrict__ A = Aall + (size_t)ls*NN*NN;
  const int t = threadIdx.x;
  const int lane = t & 63, wid = t >> 6;
  bool picked = false;
  if (t < NN) pickedsh[t] = 0;

  for (int I = 0; I < NPAN; ++I){
    const int col0 = I*PW;
    const int W = NN - col0 - PW;
    if (t == 0) nact = 0;
    __syncthreads();

    for (int e = t; e < NN*PW; e += 512){
      int r = e >> 5, c = e & 31;
      panel[r][c] = A[(size_t)r*NN + col0 + c];
    }
    __syncthreads();

    {
      float v = -1.0f; int vi = 0;
      if (t < NN && !picked){ v = fabsf(panel[t][0]); vi = t; }
      #pragma unroll
      for (int off = 32; off > 0; off >>= 1){
        float ov = __shfl_down(v, off); int oi = __shfl_down(vi, off);
        if (ov > v){ v = ov; vi = oi; }
      }
      if (lane == 0){ redv[0][wid] = v; redi[0][wid] = vi; }
    }
    __syncthreads();

    for (int c = 0; c < PW; ++c){
      const int par = c & 1;
      float bv = redv[par][0]; int p = redi[par][0];
      #pragma unroll
      for (int w = 1; w < 8; ++w)
        if (redv[par][w] > bv){ bv = redv[par][w]; p = redi[par][w]; }
      if (t == p){ picked = true; pickedsh[t] = 1; pivseq[col0+c] = t; }

      float nv = -1.0f; int ni = t;
      if (t < NN && !picked){
        const float rdia = 1.0f / panel[p][c];
        float m = panel[t][c] * rdia;
        panel[t][c] = m;
        float nxt = -1.0f;
        #pragma unroll
        for (int j = 0; j < PW; ++j){
          if (j > c){
            float u = panel[t][j] - m * panel[p][j];
            panel[t][j] = u;
            if (j == c+1) nxt = fabsf(u);
          }
        }
        nv = nxt;
      }
      #pragma unroll
      for (int off = 32; off > 0; off >>= 1){
        float ov = __shfl_down(nv, off); int oi = __shfl_down(ni, off);
        if (ov > nv){ nv = ov; ni = oi; }
      }
      if (lane == 0){ redv[par^1][wid] = nv; redi[par^1][wid] = ni; }
      __syncthreads();
    }

    if (t >= 256){
      const int jj = t - 256;
      if (jj < W){
        const int j = col0 + PW + jj;
        float u[PW];
        #pragma unroll
        for (int c = 0; c < PW; ++c) u[c] = A[(size_t)pivseq[col0+c]*NN + j];
        #pragma unroll
        for (int c = 0; c < PW; ++c){
          const int pc = pivseq[col0+c];
          float sv = u[c];
          #pragma unroll
          for (int k2 = 0; k2 < PW; ++k2)
            if (k2 < c) sv -= panel[pc][k2] * u[k2];
          u[c] = sv;
          urow[c][jj] = sv;
          A[(size_t)pc*NN + j] = sv;
        }
      }
    } else if (t < PW){
      const int cth = t;
      for (int r = cth; r < PW; ++r){
        float sv = (r == cth) ? 1.0f : 0.0f;
        const int pr = pivseq[col0+r];
        for (int k2 = cth; k2 < r; ++k2) sv -= panel[pr][k2] * linv[k2][cth];
        linv[r][cth] = sv;
      }
    } else if (t >= 64 && t < 64+PW){
      const int cth = t - 64;
      for (int r = cth; r >= 0; --r){
        float sv = (r == cth) ? 1.0f : 0.0f;
        const int pr = pivseq[col0+r];
        for (int k2 = r+1; k2 <= cth; ++k2) sv -= panel[pr][k2] * uinv[k2][cth];
        uinv[r][cth] = sv / panel[pr][r];
      }
    } else if (t >= 128 && t < 192){
      #pragma unroll
      for (int q = 0; q < 4; ++q){
        int r = (t-128)*4 + q;
        if (!pickedsh[r]){ int pos = atomicAdd(&nact, 1); actlist[pos] = r; }
      }
    }
    __syncthreads();

    for (int e = t; e < PW*PW; e += 512){
      int r = e >> 5, c2 = e & 31;
      A[(size_t)pivseq[col0+r]*NN + col0 + c2] = (r > c2) ? linv[r][c2] : uinv[r][c2];
    }
    for (int e = t; e < NN*PW; e += 512){
      int r = e >> 5, c2 = e & 31;
      if (!pickedsh[r]) A[(size_t)r*NN + col0 + c2] = panel[r][c2];
    }

    // ---- trailing update: active rows -= L21 * U12 (float4, 1 pass over cols) ----
    if (W > 0){
      for (int i0 = wid*2; i0 < W; i0 += 16){
        const int r0 = actlist[i0];
        const int r1 = actlist[i0+1];          // W is even: pair always valid
        float4* R0 = (float4*)(A + (size_t)r0*NN + col0 + PW);
        float4* R1 = (float4*)(A + (size_t)r1*NN + col0 + PW);
        if (lane*4 < W){
          float4 a0 = R0[lane];
          float4 a1 = R1[lane];
          #pragma unroll
          for (int c = 0; c < PW; ++c){
            float4 u4 = *(const float4*)&urow[c][lane*4];
            float p0 = panel[r0][c], p1 = panel[r1][c];
            a0.x -= p0*u4.x; a0.y -= p0*u4.y; a0.z -= p0*u4.z; a0.w -= p0*u4.w;
            a1.x -= p1*u4.x; a1.y -= p1*u4.y; a1.z -= p1*u4.z; a1.w -= p1*u4.w;
          }
          R0[lane] = a0;
          R1[lane] = a1;
        }
      }
    }
  }
  __syncthreads();
  if (t < NN) permAll[ls*NN + t] = pivseq[t];
}

// ---------------------------------------------------------------------------
// Kernel 3: blocked triangular solves + epilogue for ONE 64-col RHS chunk.
// 256 threads, 2 cols/thread (t&31, +32), row-group rg=t>>5. LDS 77 KB ->
// 2 independent blocks/CU: barrier stalls of one block hidden by the other.
// grid = cs*4.
// ---------------------------------------------------------------------------
__global__ __launch_bounds__(256, 2) void solve_epi_kernel(
    const float* __restrict__ Aall, const int* __restrict__ permAll,
    const float* __restrict__ rowsum,
    const float* __restrict__ C, const float* __restrict__ val,
    const int* __restrict__ bad, const float* __restrict__ rm,
    float* __restrict__ out, int s0)
{
  __shared__ float tile[NN][64];              // 64 KiB
  __shared__ float dblk[PW][PW+1];            // 4.2 KiB
  __shared__ __align__(16) float ubuf[2048];  // 8 KiB: stage / epilogue partials
  __shared__ int   perm[NN];

  int ls, c0;
  {
    const int g = blockIdx.x;
    if ((gridDim.x & 31) == 0){       // cs % 8 == 0: XCD co-location swizzle
      const int xcd = g & 7, idx = g >> 3;
      ls = xcd + 8*(idx >> 2);
      c0 = (idx & 3) * 64;
    } else {
      ls = g >> 2;
      c0 = (g & 2 ? 128 : 0) + (g & 1)*64;
    }
  }
  const int s  = s0 + ls;
  const int k  = s >> 7, b = s & 127;
  const float* __restrict__ A = Aall + (size_t)ls*NN*NN;
  const float* __restrict__ rs = rowsum + ls*NN;
  const int t = threadIdx.x;
  const int ca = t & 31;             // first owned column
  const int cb = ca + 32;            // second owned column
  const int rg = t >> 5;             // row group 0..7
  const float sk = sigmoidf_(rm[k]);

  if (t < NN) perm[t] = permAll[ls*NN + t];
  __syncthreads();

  // ---- build permuted RHS chunk on the fly (64 cols) ----
  for (int e = t; e < NN*64; e += 256){
    int i = e >> 6, c = e & 63;
    int pi = perm[i];
    float cbv = C[((size_t)b*NN + pi)*(NN+PP) + NN + c0 + c];
    float xb = sk * cbv;
    float bf = (1.0f + xb) * expf(-xb);
    if (bad[b*NN + pi]) bf = 0.0f;
    tile[i][c] = bf;
  }
  __syncthreads();

  // ---- forward: y = Linv-chain applied to Pb ----
  for (int J = 0; J < NPAN; ++J){
    const int j0 = J*PW;
    for (int e = t; e < PW*PW; e += 256){
      int r = e >> 5, c = e & 31;
      dblk[r][c] = A[(size_t)perm[j0+r]*NN + j0 + c];
    }
    __syncthreads();
    const int r0 = rg*4;
    float ya0 = tile[j0+r0+0][ca],  yb0 = tile[j0+r0+0][cb];
    float ya1 = tile[j0+r0+1][ca],  yb1 = tile[j0+r0+1][cb];
    float ya2 = tile[j0+r0+2][ca],  yb2 = tile[j0+r0+2][cb];
    float ya3 = tile[j0+r0+3][ca],  yb3 = tile[j0+r0+3][cb];
    for (int kk = 0; kk < r0; ++kk){
      float xa = tile[j0+kk][ca], xb = tile[j0+kk][cb];
      float d0 = dblk[r0+0][kk], d1 = dblk[r0+1][kk], d2 = dblk[r0+2][kk], d3 = dblk[r0+3][kk];
      ya0 += d0*xa; yb0 += d0*xb;
      ya1 += d1*xa; yb1 += d1*xb;
      ya2 += d2*xa; yb2 += d2*xb;
      ya3 += d3*xa; yb3 += d3*xb;
    }
    {
      float xa0 = tile[j0+r0][ca],  xa1 = tile[j0+r0+1][ca],  xa2 = tile[j0+r0+2][ca];
      float xb0 = tile[j0+r0][cb],  xb1 = tile[j0+r0+1][cb],  xb2 = tile[j0+r0+2][cb];
      float e10 = dblk[r0+1][r0];
      float e20 = dblk[r0+2][r0], e21 = dblk[r0+2][r0+1];
      float e30 = dblk[r0+3][r0], e31 = dblk[r0+3][r0+1], e32 = dblk[r0+3][r0+2];
      ya1 += e10*xa0;                         yb1 += e10*xb0;
      ya2 += e20*xa0 + e21*xa1;               yb2 += e20*xb0 + e21*xb1;
      ya3 += e30*xa0 + e31*xa1 + e32*xa2;     yb3 += e30*xb0 + e31*xb1 + e32*xb2;
    }
    __syncthreads();
    tile[j0+r0+0][ca]=ya0; tile[j0+r0+0][cb]=yb0;
    tile[j0+r0+1][ca]=ya1; tile[j0+r0+1][cb]=yb1;
    tile[j0+r0+2][ca]=ya2; tile[j0+r0+2][cb]=yb2;
    tile[j0+r0+3][ca]=ya3; tile[j0+r0+3][cb]=yb3;
    __syncthreads();
    const int nbelow = NN - j0 - PW;
    if (nbelow > 0){
      float xa[PW], xb[PW];
      #pragma unroll
      for (int kk = 0; kk < PW; ++kk){ xa[kk] = tile[j0+kk][ca]; xb[kk] = tile[j0+kk][cb]; }
      for (int cb2 = 0; cb2 < nbelow; cb2 += 64){
        const int rows_c = (nbelow - cb2 < 64) ? (nbelow - cb2) : 64;   // 64 or 32
        for (int e = t; e < rows_c*8; e += 256){
          int lr = e >> 3, q = e & 7;
          *(float4*)&ubuf[(lr<<5) + (q<<2)] =
            *(const float4*)(A + (size_t)perm[j0+PW+cb2+lr]*NN + j0 + (q<<2));
        }
        __syncthreads();
        for (int p2 = 0; p2 < rows_c; p2 += 8){
          const int lr = p2 + rg;
          const int ia = j0 + PW + cb2 + lr;
          const float* __restrict__ S0 = &ubuf[lr<<5];
          float acc_a = tile[ia][ca];
          float acc_b = tile[ia][cb];
          #pragma unroll
          for (int q = 0; q < 8; ++q){
            float4 a4 = *(const float4*)(S0 + (q<<2));
            acc_a -= a4.x*xa[q*4+0] + a4.y*xa[q*4+1] + a4.z*xa[q*4+2] + a4.w*xa[q*4+3];
            acc_b -= a4.x*xb[q*4+0] + a4.y*xb[q*4+1] + a4.z*xb[q*4+2] + a4.w*xb[q*4+3];
          }
          tile[ia][ca] = acc_a;
          tile[ia][cb] = acc_b;
        }
        __syncthreads();
      }
    }
  }

  // ---- backward: d = Uinv-chain applied to y ----
  for (int J = NPAN-1; J >= 0; --J){
    const int j0 = J*PW;
    for (int e = t; e < PW*PW; e += 256){
      int r = e >> 5, c = e & 31;
      dblk[r][c] = A[(size_t)perm[j0+r]*NN + j0 + c];
    }
    __syncthreads();
    const int r0 = rg*4;
    float ya0=0.f, ya1=0.f, ya2=0.f, ya3=0.f;
    float yb0=0.f, yb1=0.f, yb2=0.f, yb3=0.f;
    for (int kk = r0+4; kk < PW; ++kk){
      float xa = tile[j0+kk][ca], xb = tile[j0+kk][cb];
      float d0 = dblk[r0+0][kk], d1 = dblk[r0+1][kk], d2 = dblk[r0+2][kk], d3 = dblk[r0+3][kk];
      ya0 += d0*xa; yb0 += d0*xb;
      ya1 += d1*xa; yb1 += d1*xb;
      ya2 += d2*xa; yb2 += d2*xb;
      ya3 += d3*xa; yb3 += d3*xb;
    }
    {
      float xa0 = tile[j0+r0][ca],  xa1 = tile[j0+r0+1][ca];
      float xa2 = tile[j0+r0+2][ca], xa3 = tile[j0+r0+3][ca];
      float xb0 = tile[j0+r0][cb],  xb1 = tile[j0+r0+1][cb];
      float xb2 = tile[j0+r0+2][cb], xb3 = tile[j0+r0+3][cb];
      float e00=dblk[r0][r0], e01=dblk[r0][r0+1], e02=dblk[r0][r0+2], e03=dblk[r0][r0+3];
      float e11=dblk[r0+1][r0+1], e12=dblk[r0+1][r0+2], e13=dblk[r0+1][r0+3];
      float e22=dblk[r0+2][r0+2], e23=dblk[r0+2][r0+3];
      float e33=dblk[r0+3][r0+3];
      ya0 += e00*xa0 + e01*xa1 + e02*xa2 + e03*xa3;  yb0 += e00*xb0 + e01*xb1 + e02*xb2 + e03*xb3;
      ya1 += e11*xa1 + e12*xa2 + e13*xa3;            yb1 += e11*xb1 + e12*xb2 + e13*xb3;
      ya2 += e22*xa2 + e23*xa3;                      yb2 += e22*xb2 + e23*xb3;
      ya3 += e33*xa3;                                yb3 += e33*xb3;
    }
    __syncthreads();
    tile[j0+r0+0][ca]=ya0; tile[j0+r0+0][cb]=yb0;
    tile[j0+r0+1][ca]=ya1; tile[j0+r0+1][cb]=yb1;
    tile[j0+r0+2][ca]=ya2; tile[j0+r0+2][cb]=yb2;
    tile[j0+r0+3][ca]=ya3; tile[j0+r0+3][cb]=yb3;
    __syncthreads();
    if (j0 > 0){
      float xa[PW], xb[PW];
      #pragma unroll
      for (int kk = 0; kk < PW; ++kk){ xa[kk] = tile[j0+kk][ca]; xb[kk] = tile[j0+kk][cb]; }
      for (int cb2 = 0; cb2 < j0; cb2 += 64){
        const int rows_c = (j0 - cb2 < 64) ? (j0 - cb2) : 64;   // 64 or 32
        for (int e = t; e < rows_c*8; e += 256){
          int lr = e >> 3, q = e & 7;
          *(float4*)&ubuf[(lr<<5) + (q<<2)] =
            *(const float4*)(A + (size_t)perm[cb2+lr]*NN + j0 + (q<<2));
        }
        __syncthreads();
        for (int p2 = 0; p2 < rows_c; p2 += 8){
          const int lr = p2 + rg;
          const int ia = cb2 + lr;
          const float* __restrict__ S0 = &ubuf[lr<<5];
          float acc_a = tile[ia][ca];
          float acc_b = tile[ia][cb];
          #pragma unroll
          for (int q = 0; q < 8; ++q){
            float4 a4 = *(const float4*)(S0 + (q<<2));
            acc_a -= a4.x*xa[q*4+0] + a4.y*xa[q*4+1] + a4.z*xa[q*4+2] + a4.w*xa[q*4+3];
            acc_b -= a4.x*xb[q*4+0] + a4.y*xb[q*4+1] + a4.z*xb[q*4+2] + a4.w*xb[q*4+3];
          }
          tile[ia][ca] = acc_a;
          tile[ia][cb] = acc_b;
        }
        __syncthreads();
      }
    }
  }

  // ---- epilogue: 8 row-groups x 32 rows, 2 cols/thread ----
  {
    float sdva=0.f, sabsa=0.f, s1va=0.f, s1a=0.f;
    float sdvb=0.f, sabsb=0.f, s1vb=0.f, s1b=0.f;
    const int pa = c0 + ca, pb = c0 + cb;
    for (int j = rg*32; j < rg*32 + 32; ++j){
      float v = val[(b*NN + j)*KK + k];
      if (v != v) v = 0.0f;
      const float rsj = rs[j];
      const bool bj = bad[b*NN + j] != 0;
      float da = tile[j][ca];
      float cba = C[((size_t)b*NN + j)*(NN+PP) + NN + pa];
      float xba = sk*cba;
      float boa = (1.0f+xba)*expf(-xba);
      if (bj) boa = 0.0f;
      float d1a = boa / rsj;
      sdva += da*v; sabsa += fabsf(da); s1va += d1a*v; s1a += d1a;
      float db = tile[j][cb];
      float cbb = C[((size_t)b*NN + j)*(NN+PP) + NN + pb];
      float xbb = sk*cbb;
      float bob = (1.0f+xbb)*expf(-xbb);
      if (bj) bob = 0.0f;
      float d1b = bob / rsj;
      sdvb += db*v; sabsb += fabsf(db); s1vb += d1b*v; s1b += d1b;
    }
    __syncthreads();   // ubuf (stage) dead; reuse as ep partials [4 qty][8 grp][64 col]
    ubuf[(0*8 + rg)*64 + ca] = sdva;  ubuf[(0*8 + rg)*64 + cb] = sdvb;
    ubuf[(1*8 + rg)*64 + ca] = sabsa; ubuf[(1*8 + rg)*64 + cb] = sabsb;
    ubuf[(2*8 + rg)*64 + ca] = s1va;  ubuf[(2*8 + rg)*64 + cb] = s1vb;
    ubuf[(3*8 + rg)*64 + ca] = s1a;   ubuf[(3*8 + rg)*64 + cb] = s1b;
  }
  __syncthreads();
  if (t < 64){
    float sdv=0.f, sabs=0.f, s1v=0.f, s1=0.f;
    #pragma unroll
    for (int w = 0; w < 8; ++w){
      sdv  += ubuf[(0*8 + w)*64 + t];
      sabs += ubuf[(1*8 + w)*64 + t];
      s1v  += ubuf[(2*8 + w)*64 + t];
      s1   += ubuf[(3*8 + w)*64 + t];
    }
    float wg    = fminf(fmaxf((sabs - 1.0f)*2.0f, 0.0f), 1.0f);
    float denom = fmaxf(s1, 1.0f);
    out[((size_t)b*PP + c0 + t)*KK + k] = (1.0f - wg)*sdv + (wg/denom)*s1v;
  }
}

// ---------------------------------------------------------------------------
extern "C" void kernel_launch(void* const* d_in, const int* in_sizes, int n_in,
                              void* d_out, int out_size, void* d_ws, size_t ws_size,
                              hipStream_t stream)
{
  (void)in_sizes; (void)n_in; (void)out_size;
  const float* C    = (const float*)d_in[0];
  const float* val  = (const float*)d_in[1];
  const float* rm   = (const float*)d_in[2];
  const float* epsp = (const float*)d_in[3];
  const int*   bad  = (const int*)d_in[4];
  float* out = (float*)d_out;

  // per-system workspace: A (NN*NN f32) + rowsum (NN f32) + perm (NN i32)
  const size_t per_sys = (size_t)NN*NN*4 + (size_t)NN*4 + (size_t)NN*4;
  int chunk = (int)(ws_size / per_sys);
  if (chunk < 1)    chunk = 1;
  if (chunk > NSYS) chunk = NSYS;

  float* ws     = (float*)d_ws;
  float* A      = ws;
  float* rowsum = A + (size_t)chunk*NN*NN;
  int*   perm   = (int*)(rowsum + (size_t)chunk*NN);

  for (int s0 = 0; s0 < NSYS; s0 += chunk){
    int cs = (NSYS - s0 < chunk) ? (NSYS - s0) : chunk;
    build_kernel<<<cs*NN, 256, 0, stream>>>(C, rm, epsp, bad, A, rowsum, s0);
    lu_kernel<<<cs, 512, 0, stream>>>(A, perm);
    solve_epi_kernel<<<cs*4, 256, 0, stream>>>(A, perm, rowsum, C, val, bad, rm, out, s0);
  }
}